// Round 7
// baseline (110.807 us; speedup 1.0000x reference)
//
#include <hip/hip_runtime.h>

#define LLEN 65536
#define CIN 64
#define COUT 64
#define LTILE 1024   // l positions per block (4 waves x 64 lanes x 4 l)

typedef float f32x4 __attribute__((ext_vector_type(4)));
typedef unsigned long long u64;

// Per-co constant record, 64 B so the co-loop fetch is one s_load_dwordx16.
struct __align__(64) WRec {
    u64 p0, p1, p2;                 // sign words (bit=1 iff w>0) for k=0,1,2
    float A;    // wscale * sum_nnz + bias
    float S;    // -2 * wscale
    float Bv, G, Z;                 // RPReLU beta, gamma, zeta
    float f0, f2;                   // 0.5*nnz(k=0), 0.5*nnz(k=2) edge fixups
    float pad[3];
};

__global__ void pack_weights(const float* __restrict__ w,
                             const float* __restrict__ wscale,
                             const float* __restrict__ bias,
                             const float* __restrict__ beta,
                             const float* __restrict__ gamma,
                             const float* __restrict__ zeta,
                             WRec* __restrict__ rec) {
    int co = threadIdx.x;
    if (co >= COUT) return;
    u64 p[3];
    int nnz[3], ntot = 0;
    for (int k = 0; k < 3; ++k) {
        u64 pos = 0ull, nz = 0ull;
        for (int ci = 0; ci < CIN; ++ci) {
            float wv = w[co * (CIN * 3) + ci * 3 + k];
            pos |= ((u64)(wv > 0.0f)) << ci;
            nz  |= ((u64)(wv != 0.0f)) << ci;
        }
        p[k] = pos;
        nnz[k] = __popcll(nz);
        ntot += nnz[k];
    }
    WRec r;
    float s = wscale[co];
    r.p0 = p[0]; r.p1 = p[1]; r.p2 = p[2];
    r.A  = s * (float)ntot + bias[co];
    r.S  = -2.0f * s;
    r.Bv = beta[co]; r.G = gamma[co]; r.Z = zeta[co];
    r.f0 = 0.5f * (float)nnz[0];
    r.f2 = 0.5f * (float)nnz[2];
    r.pad[0] = r.pad[1] = r.pad[2] = 0.0f;
    rec[co] = r;
}

__device__ __forceinline__ float rprelu(float y, float B, float G, float Z) {
    float xs = y - G;
    return (y > G) ? (xs + Z) : fmaf(B, xs, Z);
}

// EDGE: 0 = interior block, 1 = contains l==0, 2 = contains l==LLEN-1.
template <int EDGE>
__device__ __forceinline__ void co_loop(const WRec* __restrict__ rec,
                                        u64 xq0, u64 xq1, u64 xq2,
                                        u64 xq3, u64 xq4, u64 xq5,
                                        bool fixlane, float* __restrict__ outp) {
    #pragma unroll 4
    for (int co = 0; co < COUT; ++co) {
        const WRec r = rec[co];   // uniform address -> scalar loads
        float fx = (float)(__popcll(xq0 ^ r.p0) + __popcll(xq1 ^ r.p1)
                         + __popcll(xq2 ^ r.p2));
        float fy = (float)(__popcll(xq1 ^ r.p0) + __popcll(xq2 ^ r.p1)
                         + __popcll(xq3 ^ r.p2));
        float fz = (float)(__popcll(xq2 ^ r.p0) + __popcll(xq3 ^ r.p1)
                         + __popcll(xq4 ^ r.p2));
        float fw = (float)(__popcll(xq3 ^ r.p0) + __popcll(xq4 ^ r.p1)
                         + __popcll(xq5 ^ r.p2));
        if (EDGE == 1 && fixlane)   // l==0 (o.x): k=0 term is zero padding
            fx = (float)(__popcll(xq1 ^ r.p1) + __popcll(xq2 ^ r.p2)) + r.f0;
        if (EDGE == 2 && fixlane)   // l==LLEN-1 (o.w): k=2 term is zero padding
            fw = (float)(__popcll(xq3 ^ r.p0) + __popcll(xq4 ^ r.p1)) + r.f2;
        f32x4 o;
        o.x = rprelu(fmaf(r.S, fx, r.A), r.Bv, r.G, r.Z);
        o.y = rprelu(fmaf(r.S, fy, r.A), r.Bv, r.G, r.Z);
        o.z = rprelu(fmaf(r.S, fz, r.A), r.Bv, r.G, r.Z);
        o.w = rprelu(fmaf(r.S, fw, r.A), r.Bv, r.G, r.Z);
        __builtin_nontemporal_store(o, (f32x4*)(outp + (size_t)co * LLEN));
    }
}

// ---------------------------------------------------------------------------
// Barrier-free main kernel. Each wave independently owns 256 l positions
// (lane owns 4). Neighbor window words come from in-wave shuffles; the two
// wave-edge words come from a strided column load + __ballot (lane == ci).
// No LDS, no __syncthreads -> every wave is an independent load/compute
// pipeline; CU scheduler interleaves memory and VALU phases across waves.
// ---------------------------------------------------------------------------
__global__ void __launch_bounds__(256, 4) bconv_kernel(
        const float* __restrict__ x,
        const float* __restrict__ alpha,
        const WRec* __restrict__ rec,
        float* __restrict__ out) {
    const int lane = threadIdx.x & 63;
    const int wid  = threadIdx.x >> 6;
    const int b = blockIdx.y;
    const int wbase = blockIdx.x * LTILE + wid * 256;   // wave's l base
    const int l = wbase + lane * 4;
    const float* xrow = x + (size_t)b * CIN * LLEN;

    // Halo column loads (wave-uniform conditions; issue early to hide latency)
    const float alv = alpha[lane];          // lane == ci
    const int llo = wbase - 1, lhi = wbase + 256;
    float vlo = 0.0f, vhi = 0.0f;
    if (llo >= 0)   vlo = xrow[(size_t)lane * LLEN + llo];
    if (lhi < LLEN) vhi = xrow[(size_t)lane * LLEN + lhi];

    // Main loads + pack: thread covers l .. l+3 -> words w0..w3
    const float* xb = xrow + l;
    u64 w0 = 0, w1 = 0, w2 = 0, w3 = 0;
    #pragma unroll 16
    for (int ci = 0; ci < CIN; ++ci) {
        const f32x4 v = *(const f32x4*)(xb + (size_t)ci * LLEN);
        const float a = alpha[ci];          // uniform -> s_load
        w0 |= ((u64)(v.x >= a)) << ci;
        w1 |= ((u64)(v.y >= a)) << ci;
        w2 |= ((u64)(v.z >= a)) << ci;
        w3 |= ((u64)(v.w >= a)) << ci;
    }

    const u64 halo_lo = __ballot(vlo >= alv);   // word(wbase-1)
    const u64 halo_hi = __ballot(vhi >= alv);   // word(wbase+256)

    // Window: xq0 = word(l-1) from lane-1's w3; xq5 = word(l+4) from lane+1's w0
    u64 up = (u64)__shfl_up((long long)w3, 1);
    u64 dn = (u64)__shfl_down((long long)w0, 1);
    const u64 xq0 = (lane == 0)  ? halo_lo : up;
    const u64 xq1 = w0, xq2 = w1, xq3 = w2, xq4 = w3;
    const u64 xq5 = (lane == 63) ? halo_hi : dn;

    float* outp = out + (size_t)b * COUT * LLEN + l;

    if (blockIdx.x == 0)
        co_loop<1>(rec, xq0, xq1, xq2, xq3, xq4, xq5, threadIdx.x == 0, outp);
    else if (blockIdx.x == gridDim.x - 1)
        co_loop<2>(rec, xq0, xq1, xq2, xq3, xq4, xq5, threadIdx.x == 255, outp);
    else
        co_loop<0>(rec, xq0, xq1, xq2, xq3, xq4, xq5, false, outp);
}

extern "C" void kernel_launch(void* const* d_in, const int* in_sizes, int n_in,
                              void* d_out, int out_size, void* d_ws, size_t ws_size,
                              hipStream_t stream) {
    const float* x      = (const float*)d_in[0];
    const float* alpha  = (const float*)d_in[1];
    const float* w      = (const float*)d_in[2];
    const float* wscale = (const float*)d_in[3];
    const float* bias   = (const float*)d_in[4];
    const float* beta   = (const float*)d_in[5];
    const float* gamma  = (const float*)d_in[6];
    const float* zeta   = (const float*)d_in[7];
    float* out = (float*)d_out;

    WRec* rec = (WRec*)d_ws;   // 64 * 64 B = 4 KB

    pack_weights<<<1, 64, 0, stream>>>(w, wscale, bias, beta, gamma, zeta, rec);

    dim3 grid(LLEN / LTILE, 16);
    bconv_kernel<<<grid, 256, 0, stream>>>(x, alpha, rec, out);
}

// Round 8
// 109.192 us; speedup vs baseline: 1.0148x; 1.0148x over previous
//
#include <hip/hip_runtime.h>

#define LLEN 65536
#define CIN 64
#define COUT 64
#define LTILE 1024   // l positions per block (256 threads x 4)

typedef float f32x4 __attribute__((ext_vector_type(4)));
typedef unsigned long long u64;

// Per-co constant record, 64 B so the co-loop fetch is one s_load_dwordx16.
struct __align__(64) WRec {
    u64 p0, p1, p2;                 // sign words (bit=1 iff w>0) for k=0,1,2
    float A;    // wscale * sum_nnz + bias
    float S;    // -2 * wscale
    float Bv, G, Z;                 // RPReLU beta, gamma, zeta
    float f0, f2;                   // 0.5*nnz(k=0), 0.5*nnz(k=2) edge fixups
    float pad[3];
};

__global__ void pack_weights(const float* __restrict__ w,
                             const float* __restrict__ wscale,
                             const float* __restrict__ bias,
                             const float* __restrict__ beta,
                             const float* __restrict__ gamma,
                             const float* __restrict__ zeta,
                             WRec* __restrict__ rec) {
    int co = threadIdx.x;
    if (co >= COUT) return;
    u64 p[3];
    int nnz[3], ntot = 0;
    for (int k = 0; k < 3; ++k) {
        u64 pos = 0ull, nz = 0ull;
        for (int ci = 0; ci < CIN; ++ci) {
            float wv = w[co * (CIN * 3) + ci * 3 + k];
            pos |= ((u64)(wv > 0.0f)) << ci;
            nz  |= ((u64)(wv != 0.0f)) << ci;
        }
        p[k] = pos;
        nnz[k] = __popcll(nz);
        ntot += nnz[k];
    }
    WRec r;
    float s = wscale[co];
    r.p0 = p[0]; r.p1 = p[1]; r.p2 = p[2];
    r.A  = s * (float)ntot + bias[co];
    r.S  = -2.0f * s;
    r.Bv = beta[co]; r.G = gamma[co]; r.Z = zeta[co];
    r.f0 = 0.5f * (float)nnz[0];
    r.f2 = 0.5f * (float)nnz[2];
    r.pad[0] = r.pad[1] = r.pad[2] = 0.0f;
    rec[co] = r;
}

__device__ __forceinline__ float rprelu(float y, float B, float G, float Z) {
    float xs = y - G;
    return (y > G) ? (xs + Z) : fmaf(B, xs, Z);
}

// EDGE: 0 = interior block, 1 = contains l==0, 2 = contains l==LLEN-1.
template <int EDGE>
__device__ __forceinline__ void co_loop(const WRec* __restrict__ rec,
                                        u64 xq0, u64 xq1, u64 xq2,
                                        u64 xq3, u64 xq4, u64 xq5,
                                        bool fixlane, float* __restrict__ outp) {
    #pragma unroll 4
    for (int co = 0; co < COUT; ++co) {
        const WRec r = rec[co];   // uniform address -> scalar loads
        float fx = (float)(__popcll(xq0 ^ r.p0) + __popcll(xq1 ^ r.p1)
                         + __popcll(xq2 ^ r.p2));
        float fy = (float)(__popcll(xq1 ^ r.p0) + __popcll(xq2 ^ r.p1)
                         + __popcll(xq3 ^ r.p2));
        float fz = (float)(__popcll(xq2 ^ r.p0) + __popcll(xq3 ^ r.p1)
                         + __popcll(xq4 ^ r.p2));
        float fw = (float)(__popcll(xq3 ^ r.p0) + __popcll(xq4 ^ r.p1)
                         + __popcll(xq5 ^ r.p2));
        if (EDGE == 1 && fixlane)   // l==0 (o.x): k=0 term is zero padding
            fx = (float)(__popcll(xq1 ^ r.p1) + __popcll(xq2 ^ r.p2)) + r.f0;
        if (EDGE == 2 && fixlane)   // l==LLEN-1 (o.w): k=2 term is zero padding
            fw = (float)(__popcll(xq3 ^ r.p0) + __popcll(xq4 ^ r.p1)) + r.f2;
        f32x4 o;
        o.x = rprelu(fmaf(r.S, fx, r.A), r.Bv, r.G, r.Z);
        o.y = rprelu(fmaf(r.S, fy, r.A), r.Bv, r.G, r.Z);
        o.z = rprelu(fmaf(r.S, fz, r.A), r.Bv, r.G, r.Z);
        o.w = rprelu(fmaf(r.S, fw, r.A), r.Bv, r.G, r.Z);
        __builtin_nontemporal_store(o, (f32x4*)(outp + (size_t)co * LLEN));
    }
}

// ---------------------------------------------------------------------------
// Main kernel (R6 structure): block = (batch b, 1024 l), thread owns 4 l,
// packed words staged in LDS, block-level halo via __ballot.
// R8 edits: __launch_bounds__(256,2) lifts the VGPR cap (44 -> ~128) and the
// pack loop is split into 4 explicit 16-row batches so ~16 f32x4 loads stay
// in flight per wave (deep VMEM pipeline) instead of ~5 at VGPR=44.
// ---------------------------------------------------------------------------
__global__ void __launch_bounds__(256, 2) bconv_kernel(
        const float* __restrict__ x,
        const float* __restrict__ alpha,
        const WRec* __restrict__ rec,
        float* __restrict__ out) {
    __shared__ u64 xw[LTILE + 2];   // xw[i] = word for l = lbase+i-1

    const int t = threadIdx.x;
    const int b = blockIdx.y;
    const int lbase = blockIdx.x * LTILE;
    const float* xrow = x + (size_t)b * CIN * LLEN;

    // Phase 1: pack. Thread t covers l = lbase+4t..+3 -> xw[4t+1 .. 4t+4]
    const float* xb = xrow + lbase + 4 * t;
    u64 w0 = 0, w1 = 0, w2 = 0, w3 = 0;
    #pragma unroll
    for (int batch = 0; batch < 4; ++batch) {
        f32x4 buf[16];
        #pragma unroll
        for (int j = 0; j < 16; ++j)
            buf[j] = *(const f32x4*)(xb + (size_t)(batch * 16 + j) * LLEN);
        #pragma unroll
        for (int j = 0; j < 16; ++j) {
            const int ci = batch * 16 + j;
            const float a = alpha[ci];             // uniform -> s_load
            w0 |= ((u64)(buf[j].x >= a)) << ci;
            w1 |= ((u64)(buf[j].y >= a)) << ci;
            w2 |= ((u64)(buf[j].z >= a)) << ci;
            w3 |= ((u64)(buf[j].w >= a)) << ci;
        }
    }
    xw[4 * t + 1] = w0;
    xw[4 * t + 2] = w1;
    xw[4 * t + 3] = w2;
    xw[4 * t + 4] = w3;

    // Halo words: wave 0 -> l = lbase-1, wave 1 -> l = lbase+LTILE.
    if (t < 64) {
        int l = lbase - 1;
        float v = (l >= 0) ? xrow[(size_t)t * LLEN + l] : 0.0f;
        u64 word = __ballot(v >= alpha[t]);
        if (t == 0) xw[0] = word;                  // garbage if l<0; fixed below
    } else if (t < 128) {
        int ci = t - 64;
        int l = lbase + LTILE;
        float v = (l < LLEN) ? xrow[(size_t)ci * LLEN + l] : 0.0f;
        u64 word = __ballot(v >= alpha[ci]);
        if (ci == 0) xw[LTILE + 1] = word;         // garbage if l>=LLEN; fixed below
    }
    __syncthreads();

    // Phase 2: window words for l = lbase+4t-1 .. +4
    const u64 xq0 = xw[4 * t + 0], xq1 = xw[4 * t + 1],
              xq2 = xw[4 * t + 2], xq3 = xw[4 * t + 3],
              xq4 = xw[4 * t + 4], xq5 = xw[4 * t + 5];
    float* outp = out + (size_t)b * COUT * LLEN + lbase + 4 * t;

    if (blockIdx.x == 0)
        co_loop<1>(rec, xq0, xq1, xq2, xq3, xq4, xq5, t == 0, outp);
    else if (blockIdx.x == gridDim.x - 1)
        co_loop<2>(rec, xq0, xq1, xq2, xq3, xq4, xq5, t == 255, outp);
    else
        co_loop<0>(rec, xq0, xq1, xq2, xq3, xq4, xq5, false, outp);
}

extern "C" void kernel_launch(void* const* d_in, const int* in_sizes, int n_in,
                              void* d_out, int out_size, void* d_ws, size_t ws_size,
                              hipStream_t stream) {
    const float* x      = (const float*)d_in[0];
    const float* alpha  = (const float*)d_in[1];
    const float* w      = (const float*)d_in[2];
    const float* wscale = (const float*)d_in[3];
    const float* bias   = (const float*)d_in[4];
    const float* beta   = (const float*)d_in[5];
    const float* gamma  = (const float*)d_in[6];
    const float* zeta   = (const float*)d_in[7];
    float* out = (float*)d_out;

    WRec* rec = (WRec*)d_ws;   // 64 * 64 B = 4 KB

    pack_weights<<<1, 64, 0, stream>>>(w, wscale, bias, beta, gamma, zeta, rec);

    dim3 grid(LLEN / LTILE, 16);
    bconv_kernel<<<grid, 256, 0, stream>>>(x, alpha, rec, out);
}